// Round 2
// baseline (694.856 us; speedup 1.0000x reference)
//
#include <hip/hip_runtime.h>
#include <math.h>

#define NPTS   1048576
#define NLEV   16
#define TPB    256
#define ROW    35          // 3 (x) + 16 levels * 2 feats
#define TBL_ENTRIES (1u << 19)

typedef float f4 __attribute__((ext_vector_type(4)));

struct LP {
    float    resf[NLEV];
    unsigned hm[NLEV];
};

__global__ __launch_bounds__(TPB)
void hashgrid_fwd(const float* __restrict__ x,
                  const float* __restrict__ tables,
                  float* __restrict__ out,
                  LP lp)
{
    __shared__ float srow[TPB * ROW];
    const int tid  = threadIdx.x;
    const int base = blockIdx.x * TPB;     // first point of this block

    // --- cooperative, coalesced load of x for this block's 256 points ---
    const float* xblk = x + (size_t)base * 3;
    for (int j = tid; j < TPB * 3; j += TPB) {
        int p = j / 3;
        int c = j - p * 3;
        srow[p * ROW + c] = xblk[j];
    }
    __syncthreads();

    const float xv0 = srow[tid * ROW + 0];
    const float xv1 = srow[tid * ROW + 1];
    const float xv2 = srow[tid * ROW + 2];

    for (int l = 0; l < NLEV; ++l) {
        const float    rf = lp.resf[l];
        const unsigned hm = lp.hm[l];
        const float2*  tbl = (const float2*)(tables + (size_t)l * TBL_ENTRIES * 2);

        const float xs0 = xv0 * rf, xs1 = xv1 * rf, xs2 = xv2 * rf;
        const float f0 = floorf(xs0), f1 = floorf(xs1), f2 = floorf(xs2);
        const float t0 = xs0 - f0, t1 = xs1 - f1, t2 = xs2 - f2;

        const unsigned a0 = (unsigned)(int)f0;
        const unsigned a1 = a0 + 1u;
        const unsigned b0 = (unsigned)(int)f1 * 2654435761u;
        const unsigned b1 = ((unsigned)(int)f1 + 1u) * 2654435761u;
        const unsigned c0 = (unsigned)(int)f2 * 805459861u;
        const unsigned c1 = ((unsigned)(int)f2 + 1u) * 805459861u;

        const float wa0 = 1.f - t0, wa1 = t0;
        const float wb0 = 1.f - t1, wb1 = t1;
        const float wc0 = 1.f - t2, wc1 = t2;

        const bool     p2   = (hm & (hm - 1u)) == 0u;   // uniform per level
        const unsigned mask = hm - 1u;

        float acc0 = 0.f, acc1 = 0.f;
        #pragma unroll
        for (int n = 0; n < 8; ++n) {
            unsigned h = ((n & 1) ? a1 : a0)
                       ^ ((n & 2) ? b1 : b0)
                       ^ ((n & 4) ? c1 : c0);
            unsigned hi = p2 ? (h & mask) : (h % hm);
            // weight product in the reference's axis order: ((w0*w1)*w2)
            float w = (((n & 1) ? wa1 : wa0) * ((n & 2) ? wb1 : wb0))
                      * ((n & 4) ? wc1 : wc0);
            float2 e = tbl[hi];
            acc0 = fmaf(e.x, w, acc0);
            acc1 = fmaf(e.y, w, acc1);
        }
        srow[tid * ROW + 3 + 2 * l] = acc0;
        srow[tid * ROW + 4 + 2 * l] = acc1;
    }
    __syncthreads();

    // --- coalesced float4 non-temporal flush: 256 rows * 35 f32 = 2240 f4 ---
    f4*       outv = (f4*)(out + (size_t)base * ROW);
    const f4* sv   = (const f4*)srow;
    for (int j = tid; j < (TPB * ROW) / 4; j += TPB) {
        __builtin_nontemporal_store(sv[j], &outv[j]);
    }
}

extern "C" void kernel_launch(void* const* d_in, const int* in_sizes, int n_in,
                              void* d_out, int out_size, void* d_ws, size_t ws_size,
                              hipStream_t stream)
{
    const float* x      = (const float*)d_in[0];
    const float* tables = (const float*)d_in[1];
    float*       out    = (float*)d_out;

    // Host-side level params with system libm -> bit-identical to CPython math.
    LP lp;
    const double beta = exp((log(2048.0) - log(16.0)) / 15.0);
    for (int i = 0; i < NLEV; ++i) {
        double r = floor(16.0 * pow(beta, (double)i));
        lp.resf[i] = (float)r;
        double h3 = r * r * r;                 // res^3, exact in double
        double cap = (double)(1u << 19);
        lp.hm[i] = (h3 < cap) ? (unsigned)h3 : (1u << 19);
    }

    const int nblocks = NPTS / TPB;            // 1048576 / 256 = 4096, no tail
    hashgrid_fwd<<<nblocks, TPB, 0, stream>>>(x, tables, out, lp);
}

// Round 3
// 676.379 us; speedup vs baseline: 1.0273x; 1.0273x over previous
//
#include <hip/hip_runtime.h>
#include <math.h>
#include <stdint.h>

#define NPTS   1048576
#define NLEV   16
#define TPB    256
#define ROW    35          // 3 (x) + 16 levels * 2 feats
#define TBL_ENTRIES (1u << 19)

struct LevelParams {
    float    resf;
    uint32_t hm;
    uint32_t is_pow2;
    uint32_t pad;
    uint64_t magic;      // Lemire fastmod: ~0ull/hm + 1 (unused when pow2)
};

struct LPAll { LevelParams lv[NLEV]; };

// One block = one (level, 256-point chunk). blockIdx % 8 selects the level
// within this launch's 8-level group -> round-robin dispatch pins each level
// to one XCD, so its <=4 MB table stays L2-resident.
__global__ __launch_bounds__(TPB)
void hashgrid_lvl(const float* __restrict__ x,
                  const float* __restrict__ tables,
                  float* __restrict__ out,
                  LPAll lp, int base)
{
    __shared__ float xs[TPB * 3];
    const int tid   = threadIdx.x;
    const int lvl   = base + (blockIdx.x & 7);
    const int chunk = blockIdx.x >> 3;
    const int p0    = chunk * TPB;

    // coalesced, non-temporal (no L2 pollution) load of this chunk's x
    const float* xblk = x + (size_t)p0 * 3;
    #pragma unroll
    for (int j = 0; j < 3; ++j) {
        int idx = tid + j * TPB;
        xs[idx] = __builtin_nontemporal_load(&xblk[idx]);
    }
    __syncthreads();

    const float xv0 = xs[tid * 3 + 0];
    const float xv1 = xs[tid * 3 + 1];
    const float xv2 = xs[tid * 3 + 2];

    const LevelParams P   = lp.lv[lvl];
    const float2*     tbl = (const float2*)(tables + (size_t)lvl * TBL_ENTRIES * 2);

    const float xs0 = xv0 * P.resf, xs1 = xv1 * P.resf, xs2 = xv2 * P.resf;
    const float f0 = floorf(xs0), f1 = floorf(xs1), f2 = floorf(xs2);
    const float t0 = xs0 - f0, t1 = xs1 - f1, t2 = xs2 - f2;

    const unsigned a0 = (unsigned)(int)f0;
    const unsigned a1 = a0 + 1u;
    const unsigned b0 = (unsigned)(int)f1 * 2654435761u;
    const unsigned b1 = ((unsigned)(int)f1 + 1u) * 2654435761u;
    const unsigned c0 = (unsigned)(int)f2 * 805459861u;
    const unsigned c1 = ((unsigned)(int)f2 + 1u) * 805459861u;

    const float wa0 = 1.f - t0, wa1 = t0;
    const float wb0 = 1.f - t1, wb1 = t1;
    const float wc0 = 1.f - t2, wc1 = t2;

    const uint32_t hmv  = P.hm;
    const uint32_t mask = hmv - 1u;
    const uint64_t M    = P.magic;
    const bool     p2   = (P.is_pow2 != 0);   // uniform per block

    float acc0 = 0.f, acc1 = 0.f;
    #pragma unroll
    for (int n = 0; n < 8; ++n) {
        unsigned h = ((n & 1) ? a1 : a0)
                   ^ ((n & 2) ? b1 : b0)
                   ^ ((n & 4) ? c1 : c0);
        unsigned hi;
        if (p2) {
            hi = h & mask;
        } else {
            // Lemire fastmod_u32: exact for all 32-bit h, hm
            uint64_t low = M * (uint64_t)h;
            hi = (uint32_t)(((__uint128_t)low * hmv) >> 64);
        }
        // weight product in the reference's axis order: ((w0*w1)*w2)
        float w = (((n & 1) ? wa1 : wa0) * ((n & 2) ? wb1 : wb0))
                  * ((n & 4) ? wc1 : wc0);
        float2 e = tbl[hi];   // regular load: keep table lines in L2
        acc0 = fmaf(e.x, w, acc0);
        acc1 = fmaf(e.y, w, acc1);
    }

    float* orow = out + (size_t)(p0 + tid) * ROW;
    __builtin_nontemporal_store(acc0, &orow[3 + 2 * lvl]);
    __builtin_nontemporal_store(acc1, &orow[4 + 2 * lvl]);
    if (lvl == 0) {
        __builtin_nontemporal_store(xv0, &orow[0]);
        __builtin_nontemporal_store(xv1, &orow[1]);
        __builtin_nontemporal_store(xv2, &orow[2]);
    }
}

extern "C" void kernel_launch(void* const* d_in, const int* in_sizes, int n_in,
                              void* d_out, int out_size, void* d_ws, size_t ws_size,
                              hipStream_t stream)
{
    const float* x      = (const float*)d_in[0];
    const float* tables = (const float*)d_in[1];
    float*       out    = (float*)d_out;

    // Host-side level params with system libm -> bit-identical to CPython math.
    LPAll lp;
    const double beta = exp((log(2048.0) - log(16.0)) / 15.0);
    for (int i = 0; i < NLEV; ++i) {
        double r = floor(16.0 * pow(beta, (double)i));
        double h3 = r * r * r;                 // res^3, exact in double
        uint32_t hm = (h3 < (double)(1u << 19)) ? (uint32_t)h3 : (1u << 19);
        lp.lv[i].resf    = (float)r;
        lp.lv[i].hm      = hm;
        lp.lv[i].is_pow2 = ((hm & (hm - 1u)) == 0u) ? 1u : 0u;
        lp.lv[i].pad     = 0;
        lp.lv[i].magic   = lp.lv[i].is_pow2 ? 0ull : (~0ull / hm + 1ull);
    }

    const int nblocks = 8 * (NPTS / TPB);      // 8 levels x 4096 chunks = 32768
    hashgrid_lvl<<<nblocks, TPB, 0, stream>>>(x, tables, out, lp, 0);
    hashgrid_lvl<<<nblocks, TPB, 0, stream>>>(x, tables, out, lp, 8);
}

// Round 4
// 484.225 us; speedup vs baseline: 1.4350x; 1.3968x over previous
//
#include <hip/hip_runtime.h>
#include <math.h>
#include <stdint.h>

#define NPTS   1048576
#define NLEV   16
#define TPB    256
#define PPT    8                   // points per thread in gather phase
#define CHUNK  (TPB * PPT)         // 2048 points per gather block
#define ROW    35                  // 3 (x) + 16 levels * 2 feats
#define TBL_ENTRIES (1u << 19)

typedef float f4 __attribute__((ext_vector_type(4)));
typedef float f2 __attribute__((ext_vector_type(2)));

struct LevelParams {
    float    resf;
    uint32_t hm;
    uint32_t is_pow2;
    uint32_t pad;
    uint64_t magic;      // Lemire fastmod: ~0ull/hm + 1 (unused when pow2)
};
struct LPAll { LevelParams lv[NLEV]; };

__device__ __forceinline__ void hash_gather_point(
    float xv0, float xv1, float xv2,
    const LevelParams& P, const float2* __restrict__ tbl,
    float& acc0, float& acc1)
{
    const float xs0 = xv0 * P.resf, xs1 = xv1 * P.resf, xs2 = xv2 * P.resf;
    const float f0 = floorf(xs0), f1 = floorf(xs1), f2v = floorf(xs2);
    const float t0 = xs0 - f0, t1 = xs1 - f1, t2 = xs2 - f2v;

    const unsigned a0 = (unsigned)(int)f0;
    const unsigned a1 = a0 + 1u;
    const unsigned b0 = (unsigned)(int)f1 * 2654435761u;
    const unsigned b1 = ((unsigned)(int)f1 + 1u) * 2654435761u;
    const unsigned c0 = (unsigned)(int)f2v * 805459861u;
    const unsigned c1 = ((unsigned)(int)f2v + 1u) * 805459861u;

    const float wa0 = 1.f - t0, wa1 = t0;
    const float wb0 = 1.f - t1, wb1 = t1;
    const float wc0 = 1.f - t2, wc1 = t2;

    const uint32_t hmv  = P.hm;
    const uint32_t mask = hmv - 1u;
    const uint64_t M    = P.magic;
    const bool     p2   = (P.is_pow2 != 0);   // uniform per block

    acc0 = 0.f; acc1 = 0.f;
    #pragma unroll
    for (int n = 0; n < 8; ++n) {
        unsigned h = ((n & 1) ? a1 : a0)
                   ^ ((n & 2) ? b1 : b0)
                   ^ ((n & 4) ? c1 : c0);
        unsigned hi;
        if (p2) {
            hi = h & mask;
        } else {
            uint64_t low = M * (uint64_t)h;       // Lemire fastmod_u32, exact
            hi = (uint32_t)(((__uint128_t)low * hmv) >> 64);
        }
        float w = (((n & 1) ? wa1 : wa0) * ((n & 2) ? wb1 : wb0))
                  * ((n & 4) ? wc1 : wc0);
        float2 e = tbl[hi];                        // regular load: stay in L2
        acc0 = fmaf(e.x, w, acc0);
        acc1 = fmaf(e.y, w, acc1);
    }
}

// Phase 1: one block = (level, 2048-point chunk); blockIdx%8 -> level ->
// XCD-pinned so each level's <=4MB table is L2-resident. Feature pairs go
// level-major into ws (perfectly coalesced, XCD-disjoint lines).
__global__ __launch_bounds__(TPB)
void hashgrid_gather(const float* __restrict__ x,
                     const float* __restrict__ tables,
                     float* __restrict__ ws,
                     LPAll lp, int base)
{
    __shared__ float xs[CHUNK * 3];
    const int tid = threadIdx.x;
    const int lvl = base + (blockIdx.x & 7);
    const int p0  = (blockIdx.x >> 3) * CHUNK;

    const float* xblk = x + (size_t)p0 * 3;
    #pragma unroll
    for (int j = 0; j < 3 * PPT; ++j)
        xs[tid + j * TPB] = __builtin_nontemporal_load(&xblk[tid + j * TPB]);
    __syncthreads();

    const LevelParams P   = lp.lv[lvl];
    const float2*     tbl = (const float2*)(tables + (size_t)lvl * TBL_ENTRIES * 2);
    f2* wrow = (f2*)ws + (size_t)lvl * NPTS + p0;

    #pragma unroll
    for (int k = 0; k < PPT; ++k) {
        const int pi = tid + k * TPB;
        float acc0, acc1;
        hash_gather_point(xs[pi * 3 + 0], xs[pi * 3 + 1], xs[pi * 3 + 2],
                          P, tbl, acc0, acc1);
        f2 v; v.x = acc0; v.y = acc1;
        __builtin_nontemporal_store(v, &wrow[pi]);   // nt: don't evict table
    }
}

// Phase 2: streaming interleave ws (level-major) + x -> row-major out,
// flushed as full float4 lines.
__global__ __launch_bounds__(TPB)
void hashgrid_interleave(const float* __restrict__ x,
                         const float* __restrict__ ws,
                         float* __restrict__ out)
{
    __shared__ float srow[TPB * ROW];
    const int tid = threadIdx.x;
    const int p0  = blockIdx.x * TPB;

    const float* xblk = x + (size_t)p0 * 3;
    #pragma unroll
    for (int j = 0; j < 3; ++j) {
        int idx = tid + j * TPB;
        int p = idx / 3, c = idx - p * 3;
        srow[p * ROW + c] = __builtin_nontemporal_load(&xblk[idx]);
    }
    const f2* wsv = (const f2*)ws;
    #pragma unroll
    for (int l = 0; l < NLEV; ++l) {
        f2 v = __builtin_nontemporal_load(&wsv[(size_t)l * NPTS + p0 + tid]);
        srow[tid * ROW + 3 + 2 * l] = v.x;
        srow[tid * ROW + 4 + 2 * l] = v.y;
    }
    __syncthreads();

    f4*       outv = (f4*)(out + (size_t)p0 * ROW);
    const f4* sv   = (const f4*)srow;
    for (int j = tid; j < (TPB * ROW) / 4; j += TPB)
        __builtin_nontemporal_store(sv[j], &outv[j]);
}

// Fallback (ws too small): round-3 direct scattered-store path.
__global__ __launch_bounds__(TPB)
void hashgrid_lvl(const float* __restrict__ x,
                  const float* __restrict__ tables,
                  float* __restrict__ out,
                  LPAll lp, int base)
{
    __shared__ float xs[TPB * 3];
    const int tid   = threadIdx.x;
    const int lvl   = base + (blockIdx.x & 7);
    const int p0    = (blockIdx.x >> 3) * TPB;

    const float* xblk = x + (size_t)p0 * 3;
    #pragma unroll
    for (int j = 0; j < 3; ++j)
        xs[tid + j * TPB] = __builtin_nontemporal_load(&xblk[tid + j * TPB]);
    __syncthreads();

    const float xv0 = xs[tid * 3 + 0];
    const float xv1 = xs[tid * 3 + 1];
    const float xv2 = xs[tid * 3 + 2];

    const LevelParams P   = lp.lv[lvl];
    const float2*     tbl = (const float2*)(tables + (size_t)lvl * TBL_ENTRIES * 2);
    float acc0, acc1;
    hash_gather_point(xv0, xv1, xv2, P, tbl, acc0, acc1);

    float* orow = out + (size_t)(p0 + tid) * ROW;
    __builtin_nontemporal_store(acc0, &orow[3 + 2 * lvl]);
    __builtin_nontemporal_store(acc1, &orow[4 + 2 * lvl]);
    if (lvl == 0) {
        __builtin_nontemporal_store(xv0, &orow[0]);
        __builtin_nontemporal_store(xv1, &orow[1]);
        __builtin_nontemporal_store(xv2, &orow[2]);
    }
}

extern "C" void kernel_launch(void* const* d_in, const int* in_sizes, int n_in,
                              void* d_out, int out_size, void* d_ws, size_t ws_size,
                              hipStream_t stream)
{
    const float* x      = (const float*)d_in[0];
    const float* tables = (const float*)d_in[1];
    float*       out    = (float*)d_out;

    // Host-side level params with system libm -> bit-identical to CPython math.
    LPAll lp;
    const double beta = exp((log(2048.0) - log(16.0)) / 15.0);
    for (int i = 0; i < NLEV; ++i) {
        double r = floor(16.0 * pow(beta, (double)i));
        double h3 = r * r * r;                 // res^3, exact in double
        uint32_t hm = (h3 < (double)(1u << 19)) ? (uint32_t)h3 : (1u << 19);
        lp.lv[i].resf    = (float)r;
        lp.lv[i].hm      = hm;
        lp.lv[i].is_pow2 = ((hm & (hm - 1u)) == 0u) ? 1u : 0u;
        lp.lv[i].pad     = 0;
        lp.lv[i].magic   = lp.lv[i].is_pow2 ? 0ull : (~0ull / hm + 1ull);
    }

    const size_t ws_need = (size_t)NLEV * NPTS * 2 * sizeof(float);  // 128 MB
    if (ws_size >= ws_need) {
        const int gblocks = 8 * (NPTS / CHUNK);   // 8 levels x 512 chunks
        hashgrid_gather<<<gblocks, TPB, 0, stream>>>(x, tables, (float*)d_ws, lp, 0);
        hashgrid_gather<<<gblocks, TPB, 0, stream>>>(x, tables, (float*)d_ws, lp, 8);
        hashgrid_interleave<<<NPTS / TPB, TPB, 0, stream>>>(x, (const float*)d_ws, out);
    } else {
        const int nblocks = 8 * (NPTS / TPB);
        hashgrid_lvl<<<nblocks, TPB, 0, stream>>>(x, tables, out, lp, 0);
        hashgrid_lvl<<<nblocks, TPB, 0, stream>>>(x, tables, out, lp, 8);
    }
}